// Round 23
// baseline (190.385 us; speedup 1.0000x reference)
//
#include <hip/hip_runtime.h>
#include <hip/hip_bf16.h>

// Problem constants
#define BATCH   2
#define LSEQ    2048
#define DMODEL  1024
#define DINNER  2048
#define NST     16

// Chunked scan parameters
#define LC      32
#define NCHUNK  (LSEQ / LC)   // 64

#define LOG2E   1.4426950408889634f
#define RLOG2E  0.6931471805599453f

typedef __bf16 bf16x8 __attribute__((ext_vector_type(8)));
typedef float  f32x4  __attribute__((ext_vector_type(4)));

// float -> bf16 round-to-nearest-even (inputs are finite; skip NaN path)
__device__ __forceinline__ unsigned short f2bf(float f) {
  unsigned int u = __float_as_uint(f);
  return (unsigned short)((u + 0x7FFFu + ((u >> 16) & 1u)) >> 16);
}
__device__ __forceinline__ float bf2f(unsigned short h) {
  return __uint_as_float((unsigned int)h << 16);
}

// raw v_exp_f32 (2^x) / v_log_f32 (log2 x). Args here are small-magnitude.
__device__ __forceinline__ float fast_exp2(float x) {
#if __has_builtin(__builtin_amdgcn_exp2f)
  return __builtin_amdgcn_exp2f(x);
#else
  float r; asm("v_exp_f32 %0, %1\ns_nop 0" : "=v"(r) : "v"(x)); return r;
#endif
}
__device__ __forceinline__ float fast_log2(float x) {
#if __has_builtin(__builtin_amdgcn_logf)
  return __builtin_amdgcn_logf(x);
#else
  float r; asm("v_log_f32 %0, %1\ns_nop 0" : "=v"(r) : "v"(x)); return r;
#endif
}
// softplus(x) = log(1+e^x) via native exp2/log2 (x bounded well inside range)
__device__ __forceinline__ float fast_softplus(float x) {
  float ex = fast_exp2(x * LOG2E);
  return fast_log2(1.0f + ex) * RLOG2E;
}

__device__ __forceinline__ float silu(float x) {
  return x / (1.0f + __expf(-x));
}

__device__ __forceinline__ void async_copy16(const void* g, void* l) {
  __builtin_amdgcn_global_load_lds((__attribute__((address_space(1))) void*)g,
                                   (__attribute__((address_space(3))) void*)l,
                                   16, 0, 0);
}

// ---------------------------------------------------------------------------
// f32 -> bf16 conversion: three buffers in one dispatch
// ---------------------------------------------------------------------------
__global__ __launch_bounds__(256) void cvt_tri(const float4* __restrict__ a,
                                               ushort4* __restrict__ oa, int na4,
                                               const float4* __restrict__ b,
                                               ushort4* __restrict__ ob, int nb4,
                                               const float4* __restrict__ c,
                                               ushort4* __restrict__ oc, int nc4) {
  int i = blockIdx.x * 256 + threadIdx.x;
  if (i < na4) {
    float4 v = a[i];
    ushort4 r; r.x = f2bf(v.x); r.y = f2bf(v.y); r.z = f2bf(v.z); r.w = f2bf(v.w);
    oa[i] = r;
  } else if (i - na4 < nb4) {
    int j = i - na4;
    float4 v = b[j];
    ushort4 r; r.x = f2bf(v.x); r.y = f2bf(v.y); r.z = f2bf(v.z); r.w = f2bf(v.w);
    ob[j] = r;
  } else if (i - na4 - nb4 < nc4) {
    int j = i - na4 - nb4;
    float4 v = c[j];
    ushort4 r; r.x = f2bf(v.x); r.y = f2bf(v.y); r.z = f2bf(v.z); r.w = f2bf(v.w);
    oc[j] = r;
  }
}

// ---------------------------------------------------------------------------
// bf16 NT GEMM (in_proj): BM=128, BK=64, granule XOR-swizzle (0 conflicts).
// Output split at column NSPLIT. FUSE: xi half -> fused causal conv(4)+bias+
// SiLU, u stored BF16; zz half stored BF16 raw; band-boundary rows exported
// raw fp32 to xiraw for conv_fix.
// ---------------------------------------------------------------------------
template<int N, int BN, int K, int NSPLIT>
__global__ __launch_bounds__(256, 2) void gemm_in(const unsigned short* __restrict__ A,
                                                  const unsigned short* __restrict__ B,
                                                  unsigned short* __restrict__ uo,
                                                  unsigned short* __restrict__ zo,
                                                  const float* __restrict__ cw,
                                                  const float* __restrict__ cbs,
                                                  float* __restrict__ xiraw) {
  constexpr int NB = BN / 32;
  __shared__ unsigned short As[128][64];   // 16 KB
  __shared__ unsigned short Bs[BN][64];
  const int tid  = threadIdx.x;
  const int wave = tid >> 6;
  const int lane = tid & 63;
  const int row0 = blockIdx.y * 128;
  const int col0 = blockIdx.x * BN;
  const int wr   = (wave >> 1) * 64;
  const int wc   = (wave & 1)  * (BN / 2);
  const int fr   = lane & 15;
  const int fq   = lane >> 4;

  f32x4 acc[4][NB] = {};

  const int sr  = wave * 8 + (lane >> 3);  // staging row-in-chunk 0..31
  const int gp  = lane & 7;
  const int sgl = gp ^ (sr & 7);           // inverse-swizzled source granule
  const unsigned short* gA = A + (size_t)(row0 + sr) * K + sgl * 8;
  const unsigned short* gB = B + (size_t)(col0 + sr) * K + sgl * 8;
  char* lA = (char*)As + wave * 1024;
  char* lB = (char*)Bs + wave * 1024;

  const int rsw = (fr & 7);                // read-side swizzle term

  for (int k0 = 0; k0 < K; k0 += 64) {
    #pragma unroll
    for (int c = 0; c < 4; ++c)
      async_copy16(gA + (size_t)c * 32 * K + k0, lA + c * 4096);
    #pragma unroll
    for (int c = 0; c < NB; ++c)
      async_copy16(gB + (size_t)c * 32 * K + k0, lB + c * 4096);
    __syncthreads();

    #pragma unroll
    for (int kk = 0; kk < 2; ++kk) {
      bf16x8 af[4], bfr[NB];
      #pragma unroll
      for (int i = 0; i < 4; ++i)
        af[i] = *(const bf16x8*)((const char*)As + (wr + i * 16 + fr) * 128 +
                                 (((kk << 2) | fq) ^ rsw) * 16);
      #pragma unroll
      for (int j = 0; j < NB; ++j)
        bfr[j] = *(const bf16x8*)((const char*)Bs + (wc + j * 16 + fr) * 128 +
                                  (((kk << 2) | fq) ^ rsw) * 16);
      #pragma unroll
      for (int i = 0; i < 4; ++i)
        #pragma unroll
        for (int j = 0; j < NB; ++j)
          acc[i][j] = __builtin_amdgcn_mfma_f32_16x16x32_bf16(af[i], bfr[j], acc[i][j], 0, 0, 0);
    }
    __syncthreads();
  }

  if (col0 < NSPLIT) {
    // fused conv + SiLU into u (bf16); raw xi boundary exports into xiraw.
    const int src = (lane + 48) & 63;    // == lane-16 for fq>0, lane+48 for fq==0
    #pragma unroll
    for (int j = 0; j < NB; ++j) {
      const int d = col0 + wc + j * 16 + fr;
      const float4 w = *(const float4*)(cw + d * 4);
      const float cb0 = cbs[d];
      float pr1 = 0.f, pr2 = 0.f, pr3 = 0.f;   // acc[i-1][j][1..3]
      #pragma unroll
      for (int i = 0; i < 4; ++i) {
        float a0 = acc[i][j][0], a1 = acc[i][j][1];
        float a2 = acc[i][j][2], a3 = acc[i][j][3];
        float e1 = (fq == 3) ? pr1 : a1;
        float e2 = (fq == 3) ? pr2 : a2;
        float e3 = (fq == 3) ? pr3 : a3;
        float xm1 = __shfl(e3, src);   // row q0-1
        float xm2 = __shfl(e2, src);   // row q0-2
        float xm3 = __shfl(e1, src);   // row q0-3
        const int rowq = row0 + wr + i * 16 + fq * 4;
        float c0v = cb0 + w.x * xm3 + w.y * xm2 + w.z * xm1 + w.w * a0;
        float c1v = cb0 + w.x * xm2 + w.y * xm1 + w.z * a0  + w.w * a1;
        float c2v = cb0 + w.x * xm1 + w.y * a0  + w.z * a1  + w.w * a2;
        float c3v = cb0 + w.x * a0  + w.y * a1  + w.z * a2  + w.w * a3;
        uo[(size_t)(rowq + 0) * NSPLIT + d] = f2bf(silu(c0v));  // band rows 0..2 fixed later
        uo[(size_t)(rowq + 1) * NSPLIT + d] = f2bf(silu(c1v));
        uo[(size_t)(rowq + 2) * NSPLIT + d] = f2bf(silu(c2v));
        uo[(size_t)(rowq + 3) * NSPLIT + d] = f2bf(silu(c3v));
        if (i == 0 && fq == 0) {     // band's first 3 raw rows
          xiraw[(size_t)(rowq + 0) * NSPLIT + d] = a0;
          xiraw[(size_t)(rowq + 1) * NSPLIT + d] = a1;
          xiraw[(size_t)(rowq + 2) * NSPLIT + d] = a2;
        }
        if (i == 3 && fq == 3) {     // band's last 3 raw rows (61..63)
          xiraw[(size_t)(rowq + 1) * NSPLIT + d] = a1;
          xiraw[(size_t)(rowq + 2) * NSPLIT + d] = a2;
          xiraw[(size_t)(rowq + 3) * NSPLIT + d] = a3;
        }
        pr1 = a1; pr2 = a2; pr3 = a3;
      }
    }
  } else {
    // zz half: store bf16 raw
    const int cb = col0 - NSPLIT;
    const int cstride = N - NSPLIT;
    #pragma unroll
    for (int i = 0; i < 4; ++i)
      #pragma unroll
      for (int j = 0; j < NB; ++j) {
        int row = row0 + wr + i * 16 + fq * 4;
        int col = cb + wc + j * 16 + fr;
        #pragma unroll
        for (int r = 0; r < 4; ++r)
          zo[(size_t)(row + r) * cstride + col] = f2bf(acc[i][j][r]);
      }
  }
}

// ---------------------------------------------------------------------------
// out_proj GEMM, SPLIT-K=2: BM=128, BN=32, BK=64; blockIdx.z picks K-half
// (16 K-iters each -> 2048 blocks = 8/CU for latency hiding). z=0 writes
// C directly, z=1 writes the partial buffer; add_out sums them.
// ---------------------------------------------------------------------------
template<int N, int BN, int K>
__global__ __launch_bounds__(256, 2) void gemm_out(const unsigned short* __restrict__ A,
                                                   const unsigned short* __restrict__ B,
                                                   float* __restrict__ C,
                                                   float* __restrict__ Cpart) {
  constexpr int NB = BN / 32;
  constexpr int KH = K / 2;
  __shared__ unsigned short As[128][64];   // 16 KB
  __shared__ unsigned short Bs[BN][64];
  const int tid  = threadIdx.x;
  const int wave = tid >> 6;
  const int lane = tid & 63;
  const int row0 = blockIdx.y * 128;
  const int col0 = blockIdx.x * BN;
  const int kb   = blockIdx.z * KH;
  const int wr   = (wave >> 1) * 64;
  const int wc   = (wave & 1)  * (BN / 2);
  const int fr   = lane & 15;
  const int fq   = lane >> 4;

  f32x4 acc[4][NB] = {};

  const int sr  = wave * 8 + (lane >> 3);
  const int gp  = lane & 7;
  const int sgl = gp ^ (sr & 7);
  const unsigned short* gA = A + (size_t)(row0 + sr) * K + kb + sgl * 8;
  const unsigned short* gB = B + (size_t)(col0 + sr) * K + kb + sgl * 8;
  char* lA = (char*)As + wave * 1024;
  char* lB = (char*)Bs + wave * 1024;

  const int rsw = (fr & 7);

  for (int k0 = 0; k0 < KH; k0 += 64) {
    #pragma unroll
    for (int c = 0; c < 4; ++c)
      async_copy16(gA + (size_t)c * 32 * K + k0, lA + c * 4096);
    #pragma unroll
    for (int c = 0; c < NB; ++c)
      async_copy16(gB + (size_t)c * 32 * K + k0, lB + c * 4096);
    __syncthreads();

    #pragma unroll
    for (int kk = 0; kk < 2; ++kk) {
      bf16x8 af[4], bfr[NB];
      #pragma unroll
      for (int i = 0; i < 4; ++i)
        af[i] = *(const bf16x8*)((const char*)As + (wr + i * 16 + fr) * 128 +
                                 (((kk << 2) | fq) ^ rsw) * 16);
      #pragma unroll
      for (int j = 0; j < NB; ++j)
        bfr[j] = *(const bf16x8*)((const char*)Bs + (wc + j * 16 + fr) * 128 +
                                  (((kk << 2) | fq) ^ rsw) * 16);
      #pragma unroll
      for (int i = 0; i < 4; ++i)
        #pragma unroll
        for (int j = 0; j < NB; ++j)
          acc[i][j] = __builtin_amdgcn_mfma_f32_16x16x32_bf16(af[i], bfr[j], acc[i][j], 0, 0, 0);
    }
    __syncthreads();
  }

  float* Cb = (blockIdx.z == 0) ? C : Cpart;
  #pragma unroll
  for (int i = 0; i < 4; ++i)
    #pragma unroll
    for (int j = 0; j < NB; ++j) {
      int row = row0 + wr + i * 16 + fq * 4;
      int col = col0 + wc + j * 16 + fr;
      #pragma unroll
      for (int r = 0; r < 4; ++r)
        Cb[(size_t)(row + r) * N + col] = acc[i][j][r];
    }
}

// out += part  (fp32, float4-vectorized)
__global__ __launch_bounds__(256) void add_out(float4* __restrict__ o,
                                               const float4* __restrict__ p, int n4) {
  int i = blockIdx.x * 256 + threadIdx.x;
  if (i < n4) {
    float4 a = o[i], b = p[i];
    o[i] = make_float4(a.x + b.x, a.y + b.y, a.z + b.z, a.w + b.w);
  }
}

// ---------------------------------------------------------------------------
// conv_fix: recompute u rows at 64-row band boundaries (rows 64k..64k+2)
// from the raw fp32 xi boundary exports, with causal t<3 guards; u is bf16.
// ---------------------------------------------------------------------------
__global__ __launch_bounds__(256) void conv_fix(const float* __restrict__ xiraw,
                                                const float* __restrict__ cw,
                                                const float* __restrict__ cbs,
                                                unsigned short* __restrict__ ub) {
  int idx = blockIdx.x * 256 + threadIdx.x;
  int d4  = idx & 511;
  int rr  = idx >> 9;            // 0..191 = k*3 + rho
  int k   = rr / 3;
  int rho = rr - k * 3;
  int q   = k * 64 + rho;        // global row
  int t   = q & (LSEQ - 1);
  int d   = d4 * 4;

  float4 w0 = *(const float4*)(cw + (d + 0) * 4);
  float4 w1 = *(const float4*)(cw + (d + 1) * 4);
  float4 w2 = *(const float4*)(cw + (d + 2) * 4);
  float4 w3 = *(const float4*)(cw + (d + 3) * 4);
  float4 bias = *(const float4*)(cbs + d);

  size_t base = (size_t)q * DINNER + d;
  const float4 zero = make_float4(0.f, 0.f, 0.f, 0.f);
  float4 xm3 = (t >= 3) ? *(const float4*)(xiraw + base - 3 * DINNER) : zero;
  float4 xm2 = (t >= 2) ? *(const float4*)(xiraw + base - 2 * DINNER) : zero;
  float4 xm1 = (t >= 1) ? *(const float4*)(xiraw + base - 1 * DINNER) : zero;
  float4 x00 = *(const float4*)(xiraw + base);

  float4 s;
  s.x = bias.x + w0.x * xm3.x + w0.y * xm2.x + w0.z * xm1.x + w0.w * x00.x;
  s.y = bias.y + w1.x * xm3.y + w1.y * xm2.y + w1.z * xm1.y + w1.w * x00.y;
  s.z = bias.z + w2.x * xm3.z + w2.y * xm2.z + w2.z * xm1.z + w2.w * x00.z;
  s.w = bias.w + w3.x * xm3.w + w3.y * xm2.w + w3.z * xm1.w + w3.w * x00.w;

  ushort4 r;
  r.x = f2bf(silu(s.x)); r.y = f2bf(silu(s.y));
  r.z = f2bf(silu(s.z)); r.w = f2bf(silu(s.w));
  *(ushort4*)(ub + base) = r;
}

// ---------------------------------------------------------------------------
// x_dbl: block = 4 rows, 4 waves; wave w owns e-slice {8w..8w+7}; e=32
// redundant in all waves. u read as bf16. Static-index epilogue (rule #20).
// ---------------------------------------------------------------------------
__global__ __launch_bounds__(256, 2) void xdbl_kernel(const unsigned short* __restrict__ ub,
                                                      const float* __restrict__ Wx,
                                                      float* __restrict__ dltbuf,
                                                      float* __restrict__ bc) {
  const int tid  = threadIdx.x;
  const int wave = tid >> 6;
  const int lane = tid & 63;
  const int row0 = blockIdx.x * 4;

  float acc[9][4];
  #pragma unroll
  for (int i = 0; i < 9; ++i)
    #pragma unroll
    for (int r = 0; r < 4; ++r) acc[i][r] = 0.0f;

  const unsigned short* up = ub + (size_t)row0 * DINNER + lane * 4;
  const float* wbase = Wx + (size_t)wave * 8 * DINNER + lane * 4;
  const float* w32   = Wx + (size_t)32 * DINNER + lane * 4;

  for (int kt = 0; kt < 8; ++kt) {
    const int ko = kt * 256;
    ushort4 h0 = *(const ushort4*)(up + 0 * DINNER + ko);
    ushort4 h1 = *(const ushort4*)(up + 1 * DINNER + ko);
    ushort4 h2 = *(const ushort4*)(up + 2 * DINNER + ko);
    ushort4 h3 = *(const ushort4*)(up + 3 * DINNER + ko);
    float4 uv0 = make_float4(bf2f(h0.x), bf2f(h0.y), bf2f(h0.z), bf2f(h0.w));
    float4 uv1 = make_float4(bf2f(h1.x), bf2f(h1.y), bf2f(h1.z), bf2f(h1.w));
    float4 uv2 = make_float4(bf2f(h2.x), bf2f(h2.y), bf2f(h2.z), bf2f(h2.w));
    float4 uv3 = make_float4(bf2f(h3.x), bf2f(h3.y), bf2f(h3.z), bf2f(h3.w));
    #pragma unroll
    for (int i = 0; i < 9; ++i) {
      float4 w = (i < 8) ? *(const float4*)(wbase + (size_t)i * DINNER + ko)
                         : *(const float4*)(w32 + ko);
      acc[i][0] = fmaf(uv0.x, w.x, fmaf(uv0.y, w.y, fmaf(uv0.z, w.z, fmaf(uv0.w, w.w, acc[i][0]))));
      acc[i][1] = fmaf(uv1.x, w.x, fmaf(uv1.y, w.y, fmaf(uv1.z, w.z, fmaf(uv1.w, w.w, acc[i][1]))));
      acc[i][2] = fmaf(uv2.x, w.x, fmaf(uv2.y, w.y, fmaf(uv2.z, w.z, fmaf(uv2.w, w.w, acc[i][2]))));
      acc[i][3] = fmaf(uv3.x, w.x, fmaf(uv3.y, w.y, fmaf(uv3.z, w.z, fmaf(uv3.w, w.w, acc[i][3]))));
    }
  }

  #pragma unroll
  for (int i = 0; i < 9; ++i)
    #pragma unroll
    for (int r = 0; r < 4; ++r)
      #pragma unroll
      for (int m = 1; m < 64; m <<= 1)
        acc[i][r] += __shfl_xor(acc[i][r], m);

  #pragma unroll
  for (int r = 0; r < 4; ++r) {
    if (lane == r) {
      const size_t row = row0 + r;
      #pragma unroll
      for (int i = 0; i < 8; ++i) {
        const int e = wave * 8 + i;
        if (e == 0) dltbuf[row] = acc[i][r];
        else        bc[row * 32 + (e - 1)] = acc[i][r];
      }
      if (wave == 0) bc[row * 32 + 31] = acc[8][r];
    }
  }
}

// ---------------------------------------------------------------------------
// Scan phase A. Lane = one (b, d, chunk of 32); 16 states in regs.
// u read as bf16. Emits S = sum(dl) and W = h_end; P recomputed in scanB.
// ---------------------------------------------------------------------------
__global__ __launch_bounds__(256) void scanA(const unsigned short* __restrict__ ub,
                                             const float* __restrict__ dltbuf,
                                             const float* __restrict__ bc,
                                             const float* __restrict__ Amat,
                                             const float* __restrict__ Wdt,
                                             const float* __restrict__ bdt,
                                             float* __restrict__ Sbuf,
                                             float* __restrict__ Wbuf) {
  __shared__ float sB[LC][16];   // 2 KB
  __shared__ float sdlt[LC];
  const int tid  = threadIdx.x;
  const int dblk = blockIdx.x & 7;
  const int c    = (blockIdx.x >> 3) & (NCHUNK - 1);
  const int b    = blockIdx.x >> 9;
  const int d    = dblk * 256 + tid;
  const int t0   = c * LC;

  if (tid < LC * 4) {           // 32 rows x 4 float4 = 16 floats (B-half)
    int r = tid >> 2, cp = (tid & 3) * 4;
    *(float4*)&sB[r][cp] = *(const float4*)(bc + ((size_t)(b * LSEQ + t0) + r) * 32 + cp);
  }
  if (tid < LC) sdlt[tid] = dltbuf[(size_t)b * LSEQ + t0 + tid];

  const float wd = Wdt[d];
  const float bd = bdt[d];
  float A2[16];
  #pragma unroll
  for (int i = 0; i < 4; ++i) {
    float4 v = *(const float4*)(Amat + (size_t)d * 16 + i * 4);
    A2[i*4+0] = v.x * LOG2E; A2[i*4+1] = v.y * LOG2E;
    A2[i*4+2] = v.z * LOG2E; A2[i*4+3] = v.w * LOG2E;
  }
  float h[16];
  #pragma unroll
  for (int n = 0; n < 16; ++n) h[n] = 0.0f;
  float S = 0.0f;

  size_t gu = ((size_t)b * LSEQ + t0) * DINNER + d;
  float u0 = bf2f(ub[gu]), u1 = bf2f(ub[gu + DINNER]);
  __syncthreads();

  auto body = [&](float uc, int ttl) {
    float dl = fast_softplus(fmaf(sdlt[ttl], wd, bd));
    float Bv[16];
    *(float4*)&Bv[0]  = *(const float4*)&sB[ttl][0];
    *(float4*)&Bv[4]  = *(const float4*)&sB[ttl][4];
    *(float4*)&Bv[8]  = *(const float4*)&sB[ttl][8];
    *(float4*)&Bv[12] = *(const float4*)&sB[ttl][12];
    S += dl;
    float dlu = dl * uc;
    #pragma unroll
    for (int n = 0; n < 16; ++n) {
      float ab = fast_exp2(dl * A2[n]);
      h[n] = fmaf(ab, h[n], dlu * Bv[n]);
    }
  };

  for (int tt = 0; tt < LC; tt += 2) {
    // prefetch t+2, t+3 (tail over-read stays inside d_ws; values unused)
    float u2 = bf2f(ub[gu + 2 * DINNER]), u3 = bf2f(ub[gu + 3 * DINNER]);
    body(u0, tt);
    body(u1, tt + 1);
    u0 = u2; u1 = u3;
    gu += 2 * DINNER;
  }

  const size_t gc = (size_t)(b * DINNER + d);
  Sbuf[gc * NCHUNK + c] = S;
  size_t o = (gc * NCHUNK + c) * 16;
  #pragma unroll
  for (int i = 0; i < 4; ++i)
    *(float4*)(Wbuf + o + i * 4) = make_float4(h[i*4], h[i*4+1], h[i*4+2], h[i*4+3]);
}

// ---------------------------------------------------------------------------
// Phase B: per (b,d,n) lane, combine NCHUNK summaries; P recomputed from S.
// Hin written in place over Wbuf.
// ---------------------------------------------------------------------------
__global__ __launch_bounds__(256) void scanB(const float* __restrict__ Sbuf,
                                             float* __restrict__ Wbuf,
                                             const float* __restrict__ Amat) {
  const int lane_id = blockIdx.x * 256 + threadIdx.x;
  const int gc = lane_id >> 4;
  const int n  = lane_id & 15;
  const int d  = gc & (DINNER - 1);
  const float A2 = Amat[(size_t)d * 16 + n] * LOG2E;
  const float* sp = Sbuf + (size_t)gc * NCHUNK;
  const size_t wbase = (size_t)gc * NCHUNK * 16 + n;
  float h = 0.0f;
  #pragma unroll 8
  for (int c = 0; c < NCHUNK; ++c) {
    float P = fast_exp2(A2 * sp[c]);
    float hin = h;
    h = fmaf(P, h, Wbuf[wbase + (size_t)c * 16]);
    Wbuf[wbase + (size_t)c * 16] = hin;
  }
}

// ---------------------------------------------------------------------------
// Phase C: lane = one (b, d, chunk of 32); rescan from Hin, y = sum h_n C_n,
// SiLU(z) gate (z bf16 from zb), u bf16; write y bf16 to ybf.
// ---------------------------------------------------------------------------
__global__ __launch_bounds__(256) void scanC(const unsigned short* __restrict__ ub,
                                             const unsigned short* __restrict__ zb,
                                             const float* __restrict__ dltbuf,
                                             const float* __restrict__ bc,
                                             const float* __restrict__ Amat,
                                             const float* __restrict__ Wdt,
                                             const float* __restrict__ bdt,
                                             const float* __restrict__ Hin,
                                             unsigned short* __restrict__ ybf) {
  __shared__ float sbc[LC][32];  // 4 KB
  __shared__ float sdlt[LC];
  const int tid  = threadIdx.x;
  const int dblk = blockIdx.x & 7;
  const int c    = (blockIdx.x >> 3) & (NCHUNK - 1);
  const int b    = blockIdx.x >> 9;
  const int d    = dblk * 256 + tid;
  const int t0   = c * LC;

  // 32 rows x 8 float4 = exactly 256 float4: one per thread
  ((float4*)sbc)[tid] = ((const float4*)(bc + ((size_t)b * LSEQ + t0) * 32))[tid];
  if (tid < LC) sdlt[tid] = dltbuf[(size_t)b * LSEQ + t0 + tid];

  const float wd = Wdt[d];
  const float bd = bdt[d];
  float A2[16];
  #pragma unroll
  for (int i = 0; i < 4; ++i) {
    float4 v = *(const float4*)(Amat + (size_t)d * 16 + i * 4);
    A2[i*4+0] = v.x * LOG2E; A2[i*4+1] = v.y * LOG2E;
    A2[i*4+2] = v.z * LOG2E; A2[i*4+3] = v.w * LOG2E;
  }
  const size_t o = ((size_t)(b * DINNER + d) * NCHUNK + c) * 16;
  float h[16];
  #pragma unroll
  for (int i = 0; i < 4; ++i) {
    float4 v = *(const float4*)(Hin + o + i * 4);
    h[i*4+0] = v.x; h[i*4+1] = v.y; h[i*4+2] = v.z; h[i*4+3] = v.w;
  }

  size_t gu = ((size_t)b * LSEQ + t0) * DINNER + d;   // same layout for ub, zb, ybf

  float u0 = bf2f(ub[gu]), u1 = bf2f(ub[gu + DINNER]);
  float z0 = bf2f(zb[gu]), z1 = bf2f(zb[gu + DINNER]);
  __syncthreads();

  auto body = [&](float uc, float zc, int ttl, size_t cu) {
    float dl = fast_softplus(fmaf(sdlt[ttl], wd, bd));
    float Bv[16], Cv[16];
    *(float4*)&Bv[0]  = *(const float4*)&sbc[ttl][0];
    *(float4*)&Bv[4]  = *(const float4*)&sbc[ttl][4];
    *(float4*)&Bv[8]  = *(const float4*)&sbc[ttl][8];
    *(float4*)&Bv[12] = *(const float4*)&sbc[ttl][12];
    *(float4*)&Cv[0]  = *(const float4*)&sbc[ttl][16];
    *(float4*)&Cv[4]  = *(const float4*)&sbc[ttl][20];
    *(float4*)&Cv[8]  = *(const float4*)&sbc[ttl][24];
    *(float4*)&Cv[12] = *(const float4*)&sbc[ttl][28];
    float dlu = dl * uc;
    float y = 0.0f;
    #pragma unroll
    for (int n = 0; n < 16; ++n) {
      float ab = fast_exp2(dl * A2[n]);
      h[n] = fmaf(ab, h[n], dlu * Bv[n]);
      y = fmaf(h[n], Cv[n], y);
    }
    float sig = 1.0f / (1.0f + __expf(-zc));
    ybf[cu] = f2bf(y * zc * sig);
  };

  for (int tt = 0; tt < LC; tt += 2) {
    float u2 = bf2f(ub[gu + 2 * DINNER]), u3 = bf2f(ub[gu + 3 * DINNER]);
    float z2 = bf2f(zb[gu + 2 * DINNER]), z3 = bf2f(zb[gu + 3 * DINNER]);
    body(u0, z0, tt,     gu);
    body(u1, z1, tt + 1, gu + DINNER);
    u0 = u2; u1 = u3; z0 = z2; z1 = z3;
    gu += 2 * DINNER;
  }
}

// ---------------------------------------------------------------------------
extern "C" void kernel_launch(void* const* d_in, const int* in_sizes, int n_in,
                              void* d_out, int out_size, void* d_ws, size_t ws_size,
                              hipStream_t stream) {
  const float* x      = (const float*)d_in[0];
  const float* W_in   = (const float*)d_in[1];
  const float* conv_w = (const float*)d_in[2];
  const float* conv_b = (const float*)d_in[3];
  const float* A      = (const float*)d_in[4];
  const float* W_x    = (const float*)d_in[5];
  const float* W_dt   = (const float*)d_in[6];
  const float* b_dt   = (const float*)d_in[7];
  const float* W_out  = (const float*)d_in[8];
  float* out = (float*)d_out;

  float* ws  = (float*)d_ws;
  float* xi  = ws;                                     //  8M floats  32 MB (xiraw boundary rows)
  float* zzf = xi  + (size_t)BATCH * LSEQ * DINNER;    //  slot 32 MB (zz bf16 uses half)
  float* uf  = zzf + (size_t)BATCH * LSEQ * DINNER;    //  slot 32 MB (u bf16 uses half; second
                                                       //  half reused as out_proj split-K partial)
  float* bc  = uf  + (size_t)BATCH * LSEQ * DINNER;    // 128K floats 0.5 MB
  float* Sb  = bc  + (size_t)BATCH * LSEQ * 32;        // 256K floats  1 MB
  float* dlt = Sb  + (size_t)BATCH * DINNER * NCHUNK;  //  4K floats  16 KB
  float* Wb  = dlt + (size_t)BATCH * LSEQ;             //  4M floats  16 MB

  const int ML = BATCH * LSEQ;  // 4096

  unsigned short* ub = (unsigned short*)uf;            // u, bf16 (first 16 MB of uf slot)
  unsigned short* zb = (unsigned short*)zzf;           // zz, bf16
  float* part1 = uf + (size_t)4 * 1024 * 1024;         // out_proj K-half partial (16 MB, free half)

  // bf16 aliases (regions dead at time of use):
  //   x_bf + win_bf (16 MB) over Wb — consumed by gemm_in before scanA writes Wb
  //   ybf (16 MB) over xi — xiraw boundary rows dead after conv_fix
  //   wout_bf in its own 4 MB slot after Wb
  unsigned short* x_bf    = (unsigned short*)Wb;
  unsigned short* win_bf  = (unsigned short*)Wb + (size_t)ML * DMODEL;
  unsigned short* ybf     = (unsigned short*)xi;
  unsigned short* wout_bf = (unsigned short*)(Wb + (size_t)BATCH * DINNER * NCHUNK * 16);

  // 0) convert all three bf16 operands in one dispatch
  const int na4 = ML * DMODEL / 4, nb4 = 2 * DINNER * DMODEL / 4, nc4 = DMODEL * DINNER / 4;
  cvt_tri<<<(na4 + nb4 + nc4 + 255) / 256, 256, 0, stream>>>(
      (const float4*)x, (ushort4*)x_bf, na4,
      (const float4*)W_in, (ushort4*)win_bf, nb4,
      (const float4*)W_out, (ushort4*)wout_bf, nc4);
  // 1) in_proj with FUSED conv+SiLU epilogue: u(bf16) | zz(bf16) (+ xiraw)
  gemm_in<2 * DINNER, 128, DMODEL, DINNER>
      <<<dim3((2 * DINNER) / 128, ML / 128), 256, 0, stream>>>(
      x_bf, win_bf, ub, zb, conv_w, conv_b, xi);
  // 1b) fix band-boundary rows (64k..64k+2) with causal guards
  conv_fix<<<(64 * 3 * 512) / 256, 256, 0, stream>>>(xi, conv_w, conv_b, ub);
  // 3) x_dbl
  xdbl_kernel<<<ML / 4, 256, 0, stream>>>(ub, W_x, dlt, bc);
  // 4) chunked selective scan, LC=32
  scanA<<<BATCH * NCHUNK * 8, 256, 0, stream>>>(ub, dlt, bc, A, W_dt, b_dt, Sb, Wb);
  scanB<<<(BATCH * DINNER * NST) / 256, 256, 0, stream>>>(Sb, Wb, A);
  scanC<<<BATCH * NCHUNK * 8, 256, 0, stream>>>(ub, zb, dlt, bc, A, W_dt, b_dt, Wb, ybf);
  // 5) out_proj split-K=2 (2048 blocks = 8/CU), then partial sum
  gemm_out<DMODEL, 32, DINNER>
      <<<dim3(DMODEL / 32, ML / 128, 2), 256, 0, stream>>>(
      ybf, wout_bf, out, part1);
  add_out<<<(ML * DMODEL / 4 + 255) / 256, 256, 0, stream>>>(
      (float4*)out, (const float4*)part1, ML * DMODEL / 4);
}

// Round 24
// 181.136 us; speedup vs baseline: 1.0511x; 1.0511x over previous
//
#include <hip/hip_runtime.h>
#include <hip/hip_bf16.h>

// Problem constants
#define BATCH   2
#define LSEQ    2048
#define DMODEL  1024
#define DINNER  2048
#define NST     16

// Chunked scan parameters
#define LC      32
#define NCHUNK  (LSEQ / LC)   // 64

#define LOG2E   1.4426950408889634f
#define RLOG2E  0.6931471805599453f

typedef __bf16 bf16x8 __attribute__((ext_vector_type(8)));
typedef float  f32x4  __attribute__((ext_vector_type(4)));

// float -> bf16 round-to-nearest-even (inputs are finite; skip NaN path)
__device__ __forceinline__ unsigned short f2bf(float f) {
  unsigned int u = __float_as_uint(f);
  return (unsigned short)((u + 0x7FFFu + ((u >> 16) & 1u)) >> 16);
}
__device__ __forceinline__ float bf2f(unsigned short h) {
  return __uint_as_float((unsigned int)h << 16);
}

// raw v_exp_f32 (2^x) / v_log_f32 (log2 x). Args here are small-magnitude.
__device__ __forceinline__ float fast_exp2(float x) {
#if __has_builtin(__builtin_amdgcn_exp2f)
  return __builtin_amdgcn_exp2f(x);
#else
  float r; asm("v_exp_f32 %0, %1\ns_nop 0" : "=v"(r) : "v"(x)); return r;
#endif
}
__device__ __forceinline__ float fast_log2(float x) {
#if __has_builtin(__builtin_amdgcn_logf)
  return __builtin_amdgcn_logf(x);
#else
  float r; asm("v_log_f32 %0, %1\ns_nop 0" : "=v"(r) : "v"(x)); return r;
#endif
}
// softplus(x) = log(1+e^x) via native exp2/log2 (x bounded well inside range)
__device__ __forceinline__ float fast_softplus(float x) {
  float ex = fast_exp2(x * LOG2E);
  return fast_log2(1.0f + ex) * RLOG2E;
}

__device__ __forceinline__ float silu(float x) {
  return x / (1.0f + __expf(-x));
}

__device__ __forceinline__ void async_copy16(const void* g, void* l) {
  __builtin_amdgcn_global_load_lds((__attribute__((address_space(1))) void*)g,
                                   (__attribute__((address_space(3))) void*)l,
                                   16, 0, 0);
}

// ---------------------------------------------------------------------------
// f32 -> bf16 conversion: three buffers in one dispatch
// ---------------------------------------------------------------------------
__global__ __launch_bounds__(256) void cvt_tri(const float4* __restrict__ a,
                                               ushort4* __restrict__ oa, int na4,
                                               const float4* __restrict__ b,
                                               ushort4* __restrict__ ob, int nb4,
                                               const float4* __restrict__ c,
                                               ushort4* __restrict__ oc, int nc4) {
  int i = blockIdx.x * 256 + threadIdx.x;
  if (i < na4) {
    float4 v = a[i];
    ushort4 r; r.x = f2bf(v.x); r.y = f2bf(v.y); r.z = f2bf(v.z); r.w = f2bf(v.w);
    oa[i] = r;
  } else if (i - na4 < nb4) {
    int j = i - na4;
    float4 v = b[j];
    ushort4 r; r.x = f2bf(v.x); r.y = f2bf(v.y); r.z = f2bf(v.z); r.w = f2bf(v.w);
    ob[j] = r;
  } else if (i - na4 - nb4 < nc4) {
    int j = i - na4 - nb4;
    float4 v = c[j];
    ushort4 r; r.x = f2bf(v.x); r.y = f2bf(v.y); r.z = f2bf(v.z); r.w = f2bf(v.w);
    oc[j] = r;
  }
}

// ---------------------------------------------------------------------------
// bf16 NT GEMM: BM=128, BK=64, granule XOR-swizzle (0 conflicts measured).
// Output split at column NSPLIT (tiles never straddle).
// FUSE (in_proj): xi half -> fused causal conv(4)+bias+SiLU, u stored BF16;
// zz half stored BF16 raw. Band-boundary rows (first 3 of each 64-row band)
// exported raw (fp32) to xiraw for conv_fix. out_proj (FUSE=false): fp32 C.
// ---------------------------------------------------------------------------
template<int N, int BN, int K, int NSPLIT, bool FUSE>
__global__ __launch_bounds__(256, 2) void gemm_bf16(const unsigned short* __restrict__ A,
                                                    const unsigned short* __restrict__ B,
                                                    void* __restrict__ C0,
                                                    void* __restrict__ C1,
                                                    const float* __restrict__ cw,
                                                    const float* __restrict__ cbs,
                                                    float* __restrict__ xiraw) {
  constexpr int NB = BN / 32;
  __shared__ unsigned short As[128][64];   // 16 KB
  __shared__ unsigned short Bs[BN][64];
  const int tid  = threadIdx.x;
  const int wave = tid >> 6;
  const int lane = tid & 63;
  const int row0 = blockIdx.y * 128;
  const int col0 = blockIdx.x * BN;
  const int wr   = (wave >> 1) * 64;
  const int wc   = (wave & 1)  * (BN / 2);
  const int fr   = lane & 15;
  const int fq   = lane >> 4;

  f32x4 acc[4][NB] = {};

  const int sr  = wave * 8 + (lane >> 3);  // staging row-in-chunk 0..31
  const int gp  = lane & 7;
  const int sgl = gp ^ (sr & 7);           // inverse-swizzled source granule
  const unsigned short* gA = A + (size_t)(row0 + sr) * K + sgl * 8;
  const unsigned short* gB = B + (size_t)(col0 + sr) * K + sgl * 8;
  char* lA = (char*)As + wave * 1024;
  char* lB = (char*)Bs + wave * 1024;

  const int rsw = (fr & 7);                // read-side swizzle term

  for (int k0 = 0; k0 < K; k0 += 64) {
    #pragma unroll
    for (int c = 0; c < 4; ++c)
      async_copy16(gA + (size_t)c * 32 * K + k0, lA + c * 4096);
    #pragma unroll
    for (int c = 0; c < NB; ++c)
      async_copy16(gB + (size_t)c * 32 * K + k0, lB + c * 4096);
    __syncthreads();

    #pragma unroll
    for (int kk = 0; kk < 2; ++kk) {
      bf16x8 af[4], bfr[NB];
      #pragma unroll
      for (int i = 0; i < 4; ++i)
        af[i] = *(const bf16x8*)((const char*)As + (wr + i * 16 + fr) * 128 +
                                 (((kk << 2) | fq) ^ rsw) * 16);
      #pragma unroll
      for (int j = 0; j < NB; ++j)
        bfr[j] = *(const bf16x8*)((const char*)Bs + (wc + j * 16 + fr) * 128 +
                                  (((kk << 2) | fq) ^ rsw) * 16);
      #pragma unroll
      for (int i = 0; i < 4; ++i)
        #pragma unroll
        for (int j = 0; j < NB; ++j)
          acc[i][j] = __builtin_amdgcn_mfma_f32_16x16x32_bf16(af[i], bfr[j], acc[i][j], 0, 0, 0);
    }
    __syncthreads();
  }

  if (FUSE && col0 < NSPLIT) {
    // fused conv + SiLU into u (bf16); raw xi boundary exports into xiraw.
    unsigned short* uo = (unsigned short*)C0;
    const int src = (lane + 48) & 63;    // == lane-16 for fq>0, lane+48 for fq==0
    #pragma unroll
    for (int j = 0; j < NB; ++j) {
      const int d = col0 + wc + j * 16 + fr;
      const float4 w = *(const float4*)(cw + d * 4);
      const float cb0 = cbs[d];
      float pr1 = 0.f, pr2 = 0.f, pr3 = 0.f;   // acc[i-1][j][1..3]
      #pragma unroll
      for (int i = 0; i < 4; ++i) {
        float a0 = acc[i][j][0], a1 = acc[i][j][1];
        float a2 = acc[i][j][2], a3 = acc[i][j][3];
        float e1 = (fq == 3) ? pr1 : a1;
        float e2 = (fq == 3) ? pr2 : a2;
        float e3 = (fq == 3) ? pr3 : a3;
        float xm1 = __shfl(e3, src);   // row q0-1
        float xm2 = __shfl(e2, src);   // row q0-2
        float xm3 = __shfl(e1, src);   // row q0-3
        const int rowq = row0 + wr + i * 16 + fq * 4;
        float c0v = cb0 + w.x * xm3 + w.y * xm2 + w.z * xm1 + w.w * a0;
        float c1v = cb0 + w.x * xm2 + w.y * xm1 + w.z * a0  + w.w * a1;
        float c2v = cb0 + w.x * xm1 + w.y * a0  + w.z * a1  + w.w * a2;
        float c3v = cb0 + w.x * a0  + w.y * a1  + w.z * a2  + w.w * a3;
        uo[(size_t)(rowq + 0) * NSPLIT + d] = f2bf(silu(c0v));  // band rows 0..2 fixed later
        uo[(size_t)(rowq + 1) * NSPLIT + d] = f2bf(silu(c1v));
        uo[(size_t)(rowq + 2) * NSPLIT + d] = f2bf(silu(c2v));
        uo[(size_t)(rowq + 3) * NSPLIT + d] = f2bf(silu(c3v));
        if (i == 0 && fq == 0) {     // band's first 3 raw rows
          xiraw[(size_t)(rowq + 0) * NSPLIT + d] = a0;
          xiraw[(size_t)(rowq + 1) * NSPLIT + d] = a1;
          xiraw[(size_t)(rowq + 2) * NSPLIT + d] = a2;
        }
        if (i == 3 && fq == 3) {     // band's last 3 raw rows (61..63)
          xiraw[(size_t)(rowq + 1) * NSPLIT + d] = a1;
          xiraw[(size_t)(rowq + 2) * NSPLIT + d] = a2;
          xiraw[(size_t)(rowq + 3) * NSPLIT + d] = a3;
        }
        pr1 = a1; pr2 = a2; pr3 = a3;
      }
    }
  } else if (FUSE) {
    // zz half: store bf16 raw
    unsigned short* Cb = (unsigned short*)C1;
    const int cb = col0 - NSPLIT;
    const int cstride = N - NSPLIT;
    #pragma unroll
    for (int i = 0; i < 4; ++i)
      #pragma unroll
      for (int j = 0; j < NB; ++j) {
        int row = row0 + wr + i * 16 + fq * 4;
        int col = cb + wc + j * 16 + fr;
        #pragma unroll
        for (int r = 0; r < 4; ++r)
          Cb[(size_t)(row + r) * cstride + col] = f2bf(acc[i][j][r]);
      }
  } else {
    float* Cb;
    int cb, cstride;
    if (col0 < NSPLIT) { Cb = (float*)C0; cb = col0;          cstride = NSPLIT; }
    else               { Cb = (float*)C1; cb = col0 - NSPLIT; cstride = N - NSPLIT; }
    #pragma unroll
    for (int i = 0; i < 4; ++i)
      #pragma unroll
      for (int j = 0; j < NB; ++j) {
        int row = row0 + wr + i * 16 + fq * 4;
        int col = cb + wc + j * 16 + fr;
        #pragma unroll
        for (int r = 0; r < 4; ++r)
          Cb[(size_t)(row + r) * cstride + col] = acc[i][j][r];
      }
  }
}

// ---------------------------------------------------------------------------
// conv_fix: recompute u rows at 64-row band boundaries (rows 64k..64k+2)
// from the raw fp32 xi boundary exports, with causal t<3 guards; u is bf16.
// ---------------------------------------------------------------------------
__global__ __launch_bounds__(256) void conv_fix(const float* __restrict__ xiraw,
                                                const float* __restrict__ cw,
                                                const float* __restrict__ cbs,
                                                unsigned short* __restrict__ ub) {
  int idx = blockIdx.x * 256 + threadIdx.x;
  int d4  = idx & 511;
  int rr  = idx >> 9;            // 0..191 = k*3 + rho
  int k   = rr / 3;
  int rho = rr - k * 3;
  int q   = k * 64 + rho;        // global row
  int t   = q & (LSEQ - 1);
  int d   = d4 * 4;

  float4 w0 = *(const float4*)(cw + (d + 0) * 4);
  float4 w1 = *(const float4*)(cw + (d + 1) * 4);
  float4 w2 = *(const float4*)(cw + (d + 2) * 4);
  float4 w3 = *(const float4*)(cw + (d + 3) * 4);
  float4 bias = *(const float4*)(cbs + d);

  size_t base = (size_t)q * DINNER + d;
  const float4 zero = make_float4(0.f, 0.f, 0.f, 0.f);
  float4 xm3 = (t >= 3) ? *(const float4*)(xiraw + base - 3 * DINNER) : zero;
  float4 xm2 = (t >= 2) ? *(const float4*)(xiraw + base - 2 * DINNER) : zero;
  float4 xm1 = (t >= 1) ? *(const float4*)(xiraw + base - 1 * DINNER) : zero;
  float4 x00 = *(const float4*)(xiraw + base);

  float4 s;
  s.x = bias.x + w0.x * xm3.x + w0.y * xm2.x + w0.z * xm1.x + w0.w * x00.x;
  s.y = bias.y + w1.x * xm3.y + w1.y * xm2.y + w1.z * xm1.y + w1.w * x00.y;
  s.z = bias.z + w2.x * xm3.z + w2.y * xm2.z + w2.z * xm1.z + w2.w * x00.z;
  s.w = bias.w + w3.x * xm3.w + w3.y * xm2.w + w3.z * xm1.w + w3.w * x00.w;

  ushort4 r;
  r.x = f2bf(silu(s.x)); r.y = f2bf(silu(s.y));
  r.z = f2bf(silu(s.z)); r.w = f2bf(silu(s.w));
  *(ushort4*)(ub + base) = r;
}

// ---------------------------------------------------------------------------
// x_dbl: block = 4 rows, 4 waves; wave w owns e-slice {8w..8w+7}; e=32
// redundant in all waves. u read as bf16. Static-index epilogue (rule #20).
// ---------------------------------------------------------------------------
__global__ __launch_bounds__(256, 2) void xdbl_kernel(const unsigned short* __restrict__ ub,
                                                      const float* __restrict__ Wx,
                                                      float* __restrict__ dltbuf,
                                                      float* __restrict__ bc) {
  const int tid  = threadIdx.x;
  const int wave = tid >> 6;
  const int lane = tid & 63;
  const int row0 = blockIdx.x * 4;

  float acc[9][4];
  #pragma unroll
  for (int i = 0; i < 9; ++i)
    #pragma unroll
    for (int r = 0; r < 4; ++r) acc[i][r] = 0.0f;

  const unsigned short* up = ub + (size_t)row0 * DINNER + lane * 4;
  const float* wbase = Wx + (size_t)wave * 8 * DINNER + lane * 4;
  const float* w32   = Wx + (size_t)32 * DINNER + lane * 4;

  for (int kt = 0; kt < 8; ++kt) {
    const int ko = kt * 256;
    ushort4 h0 = *(const ushort4*)(up + 0 * DINNER + ko);
    ushort4 h1 = *(const ushort4*)(up + 1 * DINNER + ko);
    ushort4 h2 = *(const ushort4*)(up + 2 * DINNER + ko);
    ushort4 h3 = *(const ushort4*)(up + 3 * DINNER + ko);
    float4 uv0 = make_float4(bf2f(h0.x), bf2f(h0.y), bf2f(h0.z), bf2f(h0.w));
    float4 uv1 = make_float4(bf2f(h1.x), bf2f(h1.y), bf2f(h1.z), bf2f(h1.w));
    float4 uv2 = make_float4(bf2f(h2.x), bf2f(h2.y), bf2f(h2.z), bf2f(h2.w));
    float4 uv3 = make_float4(bf2f(h3.x), bf2f(h3.y), bf2f(h3.z), bf2f(h3.w));
    #pragma unroll
    for (int i = 0; i < 9; ++i) {
      float4 w = (i < 8) ? *(const float4*)(wbase + (size_t)i * DINNER + ko)
                         : *(const float4*)(w32 + ko);
      acc[i][0] = fmaf(uv0.x, w.x, fmaf(uv0.y, w.y, fmaf(uv0.z, w.z, fmaf(uv0.w, w.w, acc[i][0]))));
      acc[i][1] = fmaf(uv1.x, w.x, fmaf(uv1.y, w.y, fmaf(uv1.z, w.z, fmaf(uv1.w, w.w, acc[i][1]))));
      acc[i][2] = fmaf(uv2.x, w.x, fmaf(uv2.y, w.y, fmaf(uv2.z, w.z, fmaf(uv2.w, w.w, acc[i][2]))));
      acc[i][3] = fmaf(uv3.x, w.x, fmaf(uv3.y, w.y, fmaf(uv3.z, w.z, fmaf(uv3.w, w.w, acc[i][3]))));
    }
  }

  #pragma unroll
  for (int i = 0; i < 9; ++i)
    #pragma unroll
    for (int r = 0; r < 4; ++r)
      #pragma unroll
      for (int m = 1; m < 64; m <<= 1)
        acc[i][r] += __shfl_xor(acc[i][r], m);

  #pragma unroll
  for (int r = 0; r < 4; ++r) {
    if (lane == r) {
      const size_t row = row0 + r;
      #pragma unroll
      for (int i = 0; i < 8; ++i) {
        const int e = wave * 8 + i;
        if (e == 0) dltbuf[row] = acc[i][r];
        else        bc[row * 32 + (e - 1)] = acc[i][r];
      }
      if (wave == 0) bc[row * 32 + 31] = acc[8][r];
    }
  }
}

// ---------------------------------------------------------------------------
// Scan phase A. Lane = one (b, d, chunk of 32); 16 states in regs.
// u read as bf16. Emits S = sum(dl) and W = h_end; P recomputed in scanB.
// ---------------------------------------------------------------------------
__global__ __launch_bounds__(256) void scanA(const unsigned short* __restrict__ ub,
                                             const float* __restrict__ dltbuf,
                                             const float* __restrict__ bc,
                                             const float* __restrict__ Amat,
                                             const float* __restrict__ Wdt,
                                             const float* __restrict__ bdt,
                                             float* __restrict__ Sbuf,
                                             float* __restrict__ Wbuf) {
  __shared__ float sB[LC][16];   // 2 KB
  __shared__ float sdlt[LC];
  const int tid  = threadIdx.x;
  const int dblk = blockIdx.x & 7;
  const int c    = (blockIdx.x >> 3) & (NCHUNK - 1);
  const int b    = blockIdx.x >> 9;
  const int d    = dblk * 256 + tid;
  const int t0   = c * LC;

  if (tid < LC * 4) {           // 32 rows x 4 float4 = 16 floats (B-half)
    int r = tid >> 2, cp = (tid & 3) * 4;
    *(float4*)&sB[r][cp] = *(const float4*)(bc + ((size_t)(b * LSEQ + t0) + r) * 32 + cp);
  }
  if (tid < LC) sdlt[tid] = dltbuf[(size_t)b * LSEQ + t0 + tid];

  const float wd = Wdt[d];
  const float bd = bdt[d];
  float A2[16];
  #pragma unroll
  for (int i = 0; i < 4; ++i) {
    float4 v = *(const float4*)(Amat + (size_t)d * 16 + i * 4);
    A2[i*4+0] = v.x * LOG2E; A2[i*4+1] = v.y * LOG2E;
    A2[i*4+2] = v.z * LOG2E; A2[i*4+3] = v.w * LOG2E;
  }
  float h[16];
  #pragma unroll
  for (int n = 0; n < 16; ++n) h[n] = 0.0f;
  float S = 0.0f;

  size_t gu = ((size_t)b * LSEQ + t0) * DINNER + d;
  float u0 = bf2f(ub[gu]), u1 = bf2f(ub[gu + DINNER]);
  __syncthreads();

  auto body = [&](float uc, int ttl) {
    float dl = fast_softplus(fmaf(sdlt[ttl], wd, bd));
    float Bv[16];
    *(float4*)&Bv[0]  = *(const float4*)&sB[ttl][0];
    *(float4*)&Bv[4]  = *(const float4*)&sB[ttl][4];
    *(float4*)&Bv[8]  = *(const float4*)&sB[ttl][8];
    *(float4*)&Bv[12] = *(const float4*)&sB[ttl][12];
    S += dl;
    float dlu = dl * uc;
    #pragma unroll
    for (int n = 0; n < 16; ++n) {
      float ab = fast_exp2(dl * A2[n]);
      h[n] = fmaf(ab, h[n], dlu * Bv[n]);
    }
  };

  for (int tt = 0; tt < LC; tt += 2) {
    // prefetch t+2, t+3 (tail over-read stays inside d_ws; values unused)
    float u2 = bf2f(ub[gu + 2 * DINNER]), u3 = bf2f(ub[gu + 3 * DINNER]);
    body(u0, tt);
    body(u1, tt + 1);
    u0 = u2; u1 = u3;
    gu += 2 * DINNER;
  }

  const size_t gc = (size_t)(b * DINNER + d);
  Sbuf[gc * NCHUNK + c] = S;
  size_t o = (gc * NCHUNK + c) * 16;
  #pragma unroll
  for (int i = 0; i < 4; ++i)
    *(float4*)(Wbuf + o + i * 4) = make_float4(h[i*4], h[i*4+1], h[i*4+2], h[i*4+3]);
}

// ---------------------------------------------------------------------------
// Phase B: per (b,d,n) lane, combine NCHUNK summaries; P recomputed from S.
// Hin written in place over Wbuf.
// ---------------------------------------------------------------------------
__global__ __launch_bounds__(256) void scanB(const float* __restrict__ Sbuf,
                                             float* __restrict__ Wbuf,
                                             const float* __restrict__ Amat) {
  const int lane_id = blockIdx.x * 256 + threadIdx.x;
  const int gc = lane_id >> 4;
  const int n  = lane_id & 15;
  const int d  = gc & (DINNER - 1);
  const float A2 = Amat[(size_t)d * 16 + n] * LOG2E;
  const float* sp = Sbuf + (size_t)gc * NCHUNK;
  const size_t wbase = (size_t)gc * NCHUNK * 16 + n;
  float h = 0.0f;
  #pragma unroll 8
  for (int c = 0; c < NCHUNK; ++c) {
    float P = fast_exp2(A2 * sp[c]);
    float hin = h;
    h = fmaf(P, h, Wbuf[wbase + (size_t)c * 16]);
    Wbuf[wbase + (size_t)c * 16] = hin;
  }
}

// ---------------------------------------------------------------------------
// Phase C: lane = one (b, d, chunk of 32); rescan from Hin, y = sum h_n C_n,
// SiLU(z) gate (z bf16 from zb), u bf16; write y bf16 to ybf.
// ---------------------------------------------------------------------------
__global__ __launch_bounds__(256) void scanC(const unsigned short* __restrict__ ub,
                                             const unsigned short* __restrict__ zb,
                                             const float* __restrict__ dltbuf,
                                             const float* __restrict__ bc,
                                             const float* __restrict__ Amat,
                                             const float* __restrict__ Wdt,
                                             const float* __restrict__ bdt,
                                             const float* __restrict__ Hin,
                                             unsigned short* __restrict__ ybf) {
  __shared__ float sbc[LC][32];  // 4 KB
  __shared__ float sdlt[LC];
  const int tid  = threadIdx.x;
  const int dblk = blockIdx.x & 7;
  const int c    = (blockIdx.x >> 3) & (NCHUNK - 1);
  const int b    = blockIdx.x >> 9;
  const int d    = dblk * 256 + tid;
  const int t0   = c * LC;

  // 32 rows x 8 float4 = exactly 256 float4: one per thread
  ((float4*)sbc)[tid] = ((const float4*)(bc + ((size_t)b * LSEQ + t0) * 32))[tid];
  if (tid < LC) sdlt[tid] = dltbuf[(size_t)b * LSEQ + t0 + tid];

  const float wd = Wdt[d];
  const float bd = bdt[d];
  float A2[16];
  #pragma unroll
  for (int i = 0; i < 4; ++i) {
    float4 v = *(const float4*)(Amat + (size_t)d * 16 + i * 4);
    A2[i*4+0] = v.x * LOG2E; A2[i*4+1] = v.y * LOG2E;
    A2[i*4+2] = v.z * LOG2E; A2[i*4+3] = v.w * LOG2E;
  }
  const size_t o = ((size_t)(b * DINNER + d) * NCHUNK + c) * 16;
  float h[16];
  #pragma unroll
  for (int i = 0; i < 4; ++i) {
    float4 v = *(const float4*)(Hin + o + i * 4);
    h[i*4+0] = v.x; h[i*4+1] = v.y; h[i*4+2] = v.z; h[i*4+3] = v.w;
  }

  size_t gu = ((size_t)b * LSEQ + t0) * DINNER + d;   // same layout for ub, zb, ybf

  float u0 = bf2f(ub[gu]), u1 = bf2f(ub[gu + DINNER]);
  float z0 = bf2f(zb[gu]), z1 = bf2f(zb[gu + DINNER]);
  __syncthreads();

  auto body = [&](float uc, float zc, int ttl, size_t cu) {
    float dl = fast_softplus(fmaf(sdlt[ttl], wd, bd));
    float Bv[16], Cv[16];
    *(float4*)&Bv[0]  = *(const float4*)&sbc[ttl][0];
    *(float4*)&Bv[4]  = *(const float4*)&sbc[ttl][4];
    *(float4*)&Bv[8]  = *(const float4*)&sbc[ttl][8];
    *(float4*)&Bv[12] = *(const float4*)&sbc[ttl][12];
    *(float4*)&Cv[0]  = *(const float4*)&sbc[ttl][16];
    *(float4*)&Cv[4]  = *(const float4*)&sbc[ttl][20];
    *(float4*)&Cv[8]  = *(const float4*)&sbc[ttl][24];
    *(float4*)&Cv[12] = *(const float4*)&sbc[ttl][28];
    float dlu = dl * uc;
    float y = 0.0f;
    #pragma unroll
    for (int n = 0; n < 16; ++n) {
      float ab = fast_exp2(dl * A2[n]);
      h[n] = fmaf(ab, h[n], dlu * Bv[n]);
      y = fmaf(h[n], Cv[n], y);
    }
    float sig = 1.0f / (1.0f + __expf(-zc));
    ybf[cu] = f2bf(y * zc * sig);
  };

  for (int tt = 0; tt < LC; tt += 2) {
    float u2 = bf2f(ub[gu + 2 * DINNER]), u3 = bf2f(ub[gu + 3 * DINNER]);
    float z2 = bf2f(zb[gu + 2 * DINNER]), z3 = bf2f(zb[gu + 3 * DINNER]);
    body(u0, z0, tt,     gu);
    body(u1, z1, tt + 1, gu + DINNER);
    u0 = u2; u1 = u3; z0 = z2; z1 = z3;
    gu += 2 * DINNER;
  }
}

// ---------------------------------------------------------------------------
extern "C" void kernel_launch(void* const* d_in, const int* in_sizes, int n_in,
                              void* d_out, int out_size, void* d_ws, size_t ws_size,
                              hipStream_t stream) {
  const float* x      = (const float*)d_in[0];
  const float* W_in   = (const float*)d_in[1];
  const float* conv_w = (const float*)d_in[2];
  const float* conv_b = (const float*)d_in[3];
  const float* A      = (const float*)d_in[4];
  const float* W_x    = (const float*)d_in[5];
  const float* W_dt   = (const float*)d_in[6];
  const float* b_dt   = (const float*)d_in[7];
  const float* W_out  = (const float*)d_in[8];
  float* out = (float*)d_out;

  float* ws  = (float*)d_ws;
  float* xi  = ws;                                     //  8M floats  32 MB (xiraw boundary rows)
  float* zzf = xi  + (size_t)BATCH * LSEQ * DINNER;    //  slot 32 MB (zz as bf16 uses half)
  float* uf  = zzf + (size_t)BATCH * LSEQ * DINNER;    //  slot 32 MB (u as bf16 uses half)
  float* bc  = uf  + (size_t)BATCH * LSEQ * DINNER;    // 128K floats 0.5 MB
  float* Sb  = bc  + (size_t)BATCH * LSEQ * 32;        // 256K floats  1 MB
  float* dlt = Sb  + (size_t)BATCH * DINNER * NCHUNK;  //  4K floats  16 KB
  float* Wb  = dlt + (size_t)BATCH * LSEQ;             //  4M floats  16 MB

  const int ML = BATCH * LSEQ;  // 4096

  unsigned short* ub = (unsigned short*)uf;    // u, bf16
  unsigned short* zb = (unsigned short*)zzf;   // zz, bf16

  // bf16 aliases (regions dead at time of use):
  //   x_bf + win_bf (16 MB) over Wb — consumed by gemm_in before scanA writes Wb
  //   ybf (16 MB) over xi — xiraw boundary rows dead after conv_fix
  //   wout_bf in its own 4 MB slot after Wb
  unsigned short* x_bf    = (unsigned short*)Wb;
  unsigned short* win_bf  = (unsigned short*)Wb + (size_t)ML * DMODEL;
  unsigned short* ybf     = (unsigned short*)xi;
  unsigned short* wout_bf = (unsigned short*)(Wb + (size_t)BATCH * DINNER * NCHUNK * 16);

  // 0) convert all three bf16 operands in one dispatch
  const int na4 = ML * DMODEL / 4, nb4 = 2 * DINNER * DMODEL / 4, nc4 = DMODEL * DINNER / 4;
  cvt_tri<<<(na4 + nb4 + nc4 + 255) / 256, 256, 0, stream>>>(
      (const float4*)x, (ushort4*)x_bf, na4,
      (const float4*)W_in, (ushort4*)win_bf, nb4,
      (const float4*)W_out, (ushort4*)wout_bf, nc4);
  // 1) in_proj with FUSED conv+SiLU epilogue: u(bf16) | zz(bf16) (+ xiraw)
  gemm_bf16<2 * DINNER, 128, DMODEL, DINNER, true>
      <<<dim3((2 * DINNER) / 128, ML / 128), 256, 0, stream>>>(
      x_bf, win_bf, (void*)ub, (void*)zb, conv_w, conv_b, xi);
  // 1b) fix band-boundary rows (64k..64k+2) with causal guards
  conv_fix<<<(64 * 3 * 512) / 256, 256, 0, stream>>>(xi, conv_w, conv_b, ub);
  // 3) x_dbl
  xdbl_kernel<<<ML / 4, 256, 0, stream>>>(ub, W_x, dlt, bc);
  // 4) chunked selective scan, LC=32
  scanA<<<BATCH * NCHUNK * 8, 256, 0, stream>>>(ub, dlt, bc, A, W_dt, b_dt, Sb, Wb);
  scanB<<<(BATCH * DINNER * NST) / 256, 256, 0, stream>>>(Sb, Wb, A);
  scanC<<<BATCH * NCHUNK * 8, 256, 0, stream>>>(ub, zb, dlt, bc, A, W_dt, b_dt, Wb, ybf);
  // 5) out_proj (BN=32 at BK=64 -> grid 1024 = 4 blocks/CU), fp32 out
  gemm_bf16<DMODEL, 32, DINNER, DMODEL, false>
      <<<dim3(DMODEL / 32, ML / 128), 256, 0, stream>>>(
      ybf, wout_bf, (void*)out, (void*)out, conv_w, conv_b, xi);
}